// Round 2
// baseline (89.409 us; speedup 1.0000x reference)
//
#include <hip/hip_runtime.h>
#include <hip/hip_bf16.h>

// Problem constants
constexpr int NG = 16;    // experts
constexpr int ND = 512;   // feature dim
constexpr int NB = 4096;  // batch

// Tiling
constexpr int TM = 64;
constexpr int TN = 64;
constexpr int BKT = 64;        // K-tile
constexpr int BKP = BKT + 8;   // padded LDS row (shorts) -> 2-way bank aliasing max
constexpr int NT = ND / TN;    // 8 n-tiles
constexpr int MT_CAP = NB / TM + NG;  // 80 worst-case m-tiles across experts

// meta layout in d_ws (ints)
constexpr int OFFS   = 0;    // 17 ints: per-expert offsets (exclusive scan) + total
constexpr int TILEG  = 32;   // 80 ints: tile -> expert
constexpr int TILEM  = 112;  // 80 ints: tile -> m-tile within expert
constexpr int NTILES = 192;  // 1 int
constexpr int TLIST  = 256;  // 4096 ints: compact pos -> token
constexpr size_t H_OFF = 32768;  // byte offset of H buffers in ws

typedef __attribute__((ext_vector_type(8))) short short8;
typedef __attribute__((ext_vector_type(4))) float f32x4;

__device__ inline unsigned short f2bf(float f) {
  union { float f; unsigned u; } a; a.f = f;
  unsigned u = a.u;
  return (unsigned short)((u + 0x7fffu + ((u >> 16) & 1u)) >> 16);  // RNE
}

__global__ void bin_k(const int* __restrict__ goal, int* __restrict__ meta) {
  __shared__ int cnt[NG], cur[NG];
  const int t = threadIdx.x;
  if (t < NG) cnt[t] = 0;
  __syncthreads();
  for (int i = t; i < NB; i += 256) atomicAdd(&cnt[goal[i]], 1);
  __syncthreads();
  if (t == 0) {
    int s = 0, nt = 0;
    for (int g = 0; g < NG; ++g) {
      meta[OFFS + g] = s;
      cur[g] = s;
      int c = cnt[g];
      int mts = (c + TM - 1) / TM;
      for (int m = 0; m < mts; ++m) { meta[TILEG + nt] = g; meta[TILEM + nt] = m; ++nt; }
      s += c;
    }
    meta[OFFS + NG] = s;
    meta[NTILES] = nt;
  }
  __syncthreads();
  for (int i = t; i < NB; i += 256) {
    int gg = goal[i];
    int p = atomicAdd(&cur[gg], 1);
    meta[TLIST + p] = i;
  }
}

// MODE 0: A = features (f32, gathered via tlist) -> H (bf16, compact rows)
// MODE 1: A = H (bf16, compact rows, linear)     -> out (f32, scattered to token rows)
// blockIdx.z: 0 = pi branch, 1 = vf branch
template<int MODE>
__global__ __launch_bounds__(256, 4) void mlp_gemm(
    const float* __restrict__ X,
    __hip_bfloat16* __restrict__ Hp,
    __hip_bfloat16* __restrict__ Hv,
    const float* __restrict__ Wp, const float* __restrict__ bp,
    const float* __restrict__ Wv, const float* __restrict__ bv,
    const int* __restrict__ meta,
    float* __restrict__ out)
{
  const int tileIdx = blockIdx.y;
  if (tileIdx >= meta[NTILES]) return;
  const int g   = meta[TILEG + tileIdx];
  const int mt  = meta[TILEM + tileIdx];
  const int off = meta[OFFS + g];
  const int cnt = meta[OFFS + g + 1] - off;
  const int row0 = mt * TM;
  const int n0 = blockIdx.x * TN;
  const int br = blockIdx.z;

  const float* Wt   = (br ? Wv : Wp) + (size_t)g * ND * ND;
  const float* bias = (br ? bv : bp) + (size_t)g * ND;

  __shared__ unsigned short As[2][TM][BKP];
  __shared__ unsigned short Bs[2][TN][BKP];

  const int t = threadIdx.x;
  const int r = t >> 2;   // 0..63 : row of A-tile / k-row of B-tile
  const int q = t & 3;    // 0..3  : 16-col quarter

  const int gr = row0 + r;
  const bool rowok = (gr < cnt);
  int tok = 0;
  if (MODE == 0) tok = rowok ? meta[TLIST + off + gr] : 0;
  const float* arow = X + (size_t)tok * ND;
  const __hip_bfloat16* Hin = br ? Hv : Hp;
  const unsigned short* hrow =
      (const unsigned short*)(Hin + (size_t)(off + (rowok ? gr : 0)) * ND);

  auto stage = [&](int buf, int k0) {
    // ---- A tile ----
    if (MODE == 0) {
#pragma unroll
      for (int i = 0; i < 4; ++i) {
        int c = q * 16 + i * 4;
        float4 v = make_float4(0.f, 0.f, 0.f, 0.f);
        if (rowok) v = *reinterpret_cast<const float4*>(arow + k0 + c);
        ushort4 s;
        s.x = f2bf(v.x); s.y = f2bf(v.y); s.z = f2bf(v.z); s.w = f2bf(v.w);
        *reinterpret_cast<ushort4*>(&As[buf][r][c]) = s;
      }
    } else {
#pragma unroll
      for (int i = 0; i < 2; ++i) {
        int c = q * 16 + i * 8;
        int4 v = make_int4(0, 0, 0, 0);
        if (rowok) v = *reinterpret_cast<const int4*>(hrow + k0 + c);
        *reinterpret_cast<int4*>(&As[buf][r][c]) = v;
      }
    }
    // ---- B tile (store transposed: Bs[n][k]) ----
#pragma unroll
    for (int i = 0; i < 4; ++i) {
      int c = q * 16 + i * 4;  // n offset within tile
      float4 v = *reinterpret_cast<const float4*>(Wt + (size_t)(k0 + r) * ND + n0 + c);
      Bs[buf][c + 0][r] = f2bf(v.x);
      Bs[buf][c + 1][r] = f2bf(v.y);
      Bs[buf][c + 2][r] = f2bf(v.z);
      Bs[buf][c + 3][r] = f2bf(v.w);
    }
  };

  const int lane = t & 63;
  const int wid  = t >> 6;
  const int wr   = (wid >> 1) * 32;
  const int wc   = (wid & 1) * 32;
  const int lhi  = lane >> 4;
  const int llo  = lane & 15;

  f32x4 acc[2][2];
#pragma unroll
  for (int i = 0; i < 2; ++i)
#pragma unroll
    for (int j = 0; j < 2; ++j)
      acc[i][j] = f32x4{0.f, 0.f, 0.f, 0.f};

  stage(0, 0);
  __syncthreads();

  for (int kt = 0; kt < ND / BKT; ++kt) {
    const int cb = kt & 1;
    if (kt + 1 < ND / BKT) stage(cb ^ 1, (kt + 1) * BKT);
#pragma unroll
    for (int kk = 0; kk < 2; ++kk) {
      int kb = kk * 32 + lhi * 8;
      short8 a0 = *reinterpret_cast<const short8*>(&As[cb][wr + llo][kb]);
      short8 a1 = *reinterpret_cast<const short8*>(&As[cb][wr + 16 + llo][kb]);
      short8 b0 = *reinterpret_cast<const short8*>(&Bs[cb][wc + llo][kb]);
      short8 b1 = *reinterpret_cast<const short8*>(&Bs[cb][wc + 16 + llo][kb]);
      acc[0][0] = __builtin_amdgcn_mfma_f32_16x16x32_bf16(a0, b0, acc[0][0], 0, 0, 0);
      acc[0][1] = __builtin_amdgcn_mfma_f32_16x16x32_bf16(a0, b1, acc[0][1], 0, 0, 0);
      acc[1][0] = __builtin_amdgcn_mfma_f32_16x16x32_bf16(a1, b0, acc[1][0], 0, 0, 0);
      acc[1][1] = __builtin_amdgcn_mfma_f32_16x16x32_bf16(a1, b1, acc[1][1], 0, 0, 0);
    }
    __syncthreads();
  }

  // epilogue: bias + tanh + store
  float bj0 = bias[n0 + wc + llo];
  float bj1 = bias[n0 + wc + 16 + llo];
  __hip_bfloat16* Hout = br ? Hv : Hp;
#pragma unroll
  for (int i = 0; i < 2; ++i) {
#pragma unroll
    for (int reg = 0; reg < 4; ++reg) {
      int m = wr + i * 16 + lhi * 4 + reg;
      int grr = row0 + m;
      if (grr < cnt) {
        float v0 = tanhf(acc[i][0][reg] + bj0);
        float v1 = tanhf(acc[i][1][reg] + bj1);
        if (MODE == 0) {
          size_t rowbase = (size_t)(off + grr) * ND + n0;
          Hout[rowbase + wc + llo]      = __float2bfloat16(v0);
          Hout[rowbase + wc + 16 + llo] = __float2bfloat16(v1);
        } else {
          int tok2 = meta[TLIST + off + grr];
          size_t rowbase = (size_t)br * NB * ND + (size_t)tok2 * ND + n0;
          out[rowbase + wc + llo]      = v0;
          out[rowbase + wc + 16 + llo] = v1;
        }
      }
    }
  }
}

extern "C" void kernel_launch(void* const* d_in, const int* in_sizes, int n_in,
                              void* d_out, int out_size, void* d_ws, size_t ws_size,
                              hipStream_t stream) {
  const float* features = (const float*)d_in[0];
  const float* Wp0 = (const float*)d_in[1];
  const float* bp0 = (const float*)d_in[2];
  const float* Wp1 = (const float*)d_in[3];
  const float* bp1 = (const float*)d_in[4];
  const float* Wv0 = (const float*)d_in[5];
  const float* bv0 = (const float*)d_in[6];
  const float* Wv1 = (const float*)d_in[7];
  const float* bv1 = (const float*)d_in[8];
  const int* goal  = (const int*)d_in[9];
  float* out = (float*)d_out;

  int* meta = (int*)d_ws;
  __hip_bfloat16* Hp = (__hip_bfloat16*)((char*)d_ws + H_OFF);
  __hip_bfloat16* Hv = Hp + (size_t)NB * ND;

  bin_k<<<1, 256, 0, stream>>>(goal, meta);

  dim3 grid(NT, MT_CAP, 2);
  mlp_gemm<0><<<grid, 256, 0, stream>>>(features, Hp, Hv, Wp0, bp0, Wv0, bv0, meta, out);
  mlp_gemm<1><<<grid, 256, 0, stream>>>(features, Hp, Hv, Wp1, bp1, Wv1, bv1, meta, out);
}

// Round 3
// 70.890 us; speedup vs baseline: 1.2612x; 1.2612x over previous
//
#include <hip/hip_runtime.h>
#include <hip/hip_bf16.h>

// Problem constants
constexpr int NG = 16;    // experts
constexpr int ND = 512;   // feature dim
constexpr int NB = 4096;  // batch

typedef __attribute__((ext_vector_type(8))) short short8;
typedef __attribute__((ext_vector_type(4))) float f32x4;

// ---------------- shared meta layout in d_ws (ints) ----------------
constexpr int OFFS   = 0;    // 17 ints: per-expert offsets (exclusive scan) + total
constexpr int TILEG  = 32;   // <=80 ints: tile -> expert
constexpr int TILEM  = 112;  // <=80 ints: tile -> m-tile within expert
constexpr int NTILES = 192;  // 1 int
constexpr int TLIST  = 256;  // 4096 ints: compact pos -> token

// ---------------- fast-path ws layout ----------------
constexpr size_t META_BYTES = 32768;
constexpr size_t XC_OFF = META_BYTES;                       // bf16 [4096][512]   = 4 MB
constexpr size_t HC_OFF = XC_OFF + (size_t)NB * ND * 2;     // bf16 [2][4096][512]= 8 MB
constexpr size_t WT_OFF = HC_OFF + 2ull * NB * ND * 2;      // bf16 4x[16][512][512] = 32 MB
constexpr size_t WT_TENSOR = (size_t)NG * ND * ND;          // shorts per tensor (4,194,304)
constexpr size_t FAST_WS_NEED = WT_OFF + 4 * WT_TENSOR * 2;

// legacy ws layout
constexpr size_t H_OFF = 32768;

__device__ inline unsigned short f2bf(float f) {
  union { float f; unsigned u; } a; a.f = f;
  unsigned u = a.u;
  return (unsigned short)((u + 0x7fffu + ((u >> 16) & 1u)) >> 16);  // RNE
}

__device__ inline float ftanh(float x) {
  float e = __expf(2.0f * x);                       // v_exp_f32 path
  return 1.0f - 2.0f * __builtin_amdgcn_rcpf(e + 1.0f);
  // |x| large: e=inf -> 1 ; e~0 -> -1. err ~1e-6 << bf16 rounding.
}

__device__ inline void gld16(const void* g, void* lds) {
  __builtin_amdgcn_global_load_lds(
      (const __attribute__((address_space(1))) unsigned int*)g,
      (__attribute__((address_space(3))) unsigned int*)lds, 16, 0, 0);
}

// ---------------- binning (shared by both paths; tm = m-tile size) ----------------
__global__ void bin_k(const int* __restrict__ goal, int* __restrict__ meta, int tm) {
  __shared__ int cnt[NG], cur[NG];
  const int t = threadIdx.x;
  if (t < NG) cnt[t] = 0;
  __syncthreads();
  for (int i = t; i < NB; i += 256) atomicAdd(&cnt[goal[i]], 1);
  __syncthreads();
  if (t == 0) {
    int s = 0, nt = 0;
    for (int g = 0; g < NG; ++g) {
      meta[OFFS + g] = s;
      cur[g] = s;
      int c = cnt[g];
      int mts = (c + tm - 1) / tm;
      for (int m = 0; m < mts; ++m) { meta[TILEG + nt] = g; meta[TILEM + nt] = m; ++nt; }
      s += c;
    }
    meta[OFFS + NG] = s;
    meta[NTILES] = nt;
  }
  __syncthreads();
  for (int i = t; i < NB; i += 256) {
    int gg = goal[i];
    int p = atomicAdd(&cur[gg], 1);
    meta[TLIST + p] = i;
  }
}

// ---------------- fast path: gather+convert features -> compact bf16 ----------------
__global__ void xc_k(const float* __restrict__ X, const int* __restrict__ meta,
                     unsigned short* __restrict__ Xc) {
  const int t = threadIdx.x;
  const int pos  = blockIdx.x * 4 + (t >> 6);
  const int lane = t & 63;
  const int tok = meta[TLIST + pos];
  const float* src = X + (size_t)tok * ND + lane * 8;
  float4 a = *reinterpret_cast<const float4*>(src);
  float4 b = *reinterpret_cast<const float4*>(src + 4);
  short8 o;
  o[0] = f2bf(a.x); o[1] = f2bf(a.y); o[2] = f2bf(a.z); o[3] = f2bf(a.w);
  o[4] = f2bf(b.x); o[5] = f2bf(b.y); o[6] = f2bf(b.z); o[7] = f2bf(b.w);
  *reinterpret_cast<short8*>(Xc + (size_t)pos * ND + lane * 8) = o;
}

// ---------------- fast path: convert+transpose weights -> bf16 Wt[g][n][k] ----------------
__global__ void wt_k(const float* __restrict__ s0, const float* __restrict__ s1,
                     const float* __restrict__ s2, const float* __restrict__ s3,
                     unsigned short* __restrict__ wt) {
  __shared__ float T[64][68];   // input-tile [k_local][n_local]; stride 68 dwords
  const int b = blockIdx.x;
  const int tensor = b >> 10;
  const float* S = (tensor == 0) ? s0 : (tensor == 1) ? s1 : (tensor == 2) ? s2 : s3;
  const int rem = b & 1023;
  const int g = rem >> 6;
  const int tile = rem & 63;
  const int kr0 = (tile >> 3) * 64;   // input row block (k)
  const int nc0 = (tile & 7) * 64;    // input col block (n)
  const float* Sg = S + (size_t)g * ND * ND;
  unsigned short* D = wt + ((size_t)tensor * NG + g) * ND * ND;

  const int t = threadIdx.x;
  const int r = t >> 2, q = t & 3;
#pragma unroll
  for (int i = 0; i < 4; ++i) {
    int c = q * 16 + i * 4;
    float4 v = *reinterpret_cast<const float4*>(Sg + (size_t)(kr0 + r) * ND + nc0 + c);
    *reinterpret_cast<float4*>(&T[r][c]) = v;   // dword offset r*68+c, 16B aligned
  }
  __syncthreads();
  // thread writes output row n = nc0 + r, cols k = kr0 + q*16 .. +16
  unsigned short o[16];
#pragma unroll
  for (int j = 0; j < 16; ++j) o[j] = f2bf(T[q * 16 + j][r]);
  unsigned short* drow = D + (size_t)(nc0 + r) * ND + kr0 + q * 16;
  *reinterpret_cast<short8*>(drow)     = *reinterpret_cast<short8*>(&o[0]);
  *reinterpret_cast<short8*>(drow + 8) = *reinterpret_cast<short8*>(&o[8]);
}

// ---------------- fast path GEMM: 128x128 tile, BK=64, bf16 operands ----------------
// MODE 0: A = Xc (compact bf16) -> Hc (bf16, [br][pos][n]), tanh epilogue
// MODE 1: A = Hc                -> out (f32, scattered to token rows), tanh epilogue
template<int MODE>
__global__ __launch_bounds__(256, 2) void gemm_f(
    const unsigned short* __restrict__ Abase0,
    unsigned short* __restrict__ Hc,
    const unsigned short* __restrict__ WtP,
    const unsigned short* __restrict__ WtV,
    const float* __restrict__ bp, const float* __restrict__ bv,
    const int* __restrict__ meta,
    float* __restrict__ out)
{
  __shared__ unsigned short As[2][128 * 64];
  __shared__ unsigned short Bs[2][128 * 64];

  const int tileIdx = blockIdx.y;
  if (tileIdx >= meta[NTILES]) return;
  const int g   = meta[TILEG + tileIdx];
  const int mt  = meta[TILEM + tileIdx];
  const int off = meta[OFFS + g];
  const int cnt = meta[OFFS + g + 1] - off;
  const int row0 = mt * 128;
  const int n0 = blockIdx.x * 128;
  const int br = blockIdx.z;

  const unsigned short* W = (br ? WtV : WtP) + (size_t)g * ND * ND;
  const float* bias = (br ? bv : bp) + (size_t)g * ND;
  const unsigned short* Ab = Abase0 + (MODE == 1 ? (size_t)br * NB * ND : 0);

  const int t = threadIdx.x;
  const int lane = t & 63;
  const int wid  = t >> 6;

  // staging geometry: chunk c covers tile bytes [c*4096 + wid*1024 + lane*16, +16)
  // tile row r = o>>7 (128 B rows of 64 bf16); logical col pre-swizzled so that a
  // swizzled ds_read sees layout col_bytes ^ ((r&7)<<4).
  int ro[4], so[4];
#pragma unroll
  for (int c = 0; c < 4; ++c) {
    int o = c * 4096 + wid * 1024 + lane * 16;
    int r = o >> 7, w = o & 127;
    ro[c] = r;
    so[c] = (w ^ ((r & 7) << 4)) >> 1;   // source element offset within row
  }

  auto stage = [&](int buf, int k0) {
#pragma unroll
    for (int c = 0; c < 4; ++c) {
      const int r = ro[c];
      if (row0 + r < cnt)
        gld16(Ab + (size_t)(off + row0 + r) * ND + k0 + so[c],
              (char*)&As[buf][0] + c * 4096 + wid * 1024);
      gld16(W + (size_t)(n0 + r) * ND + k0 + so[c],
            (char*)&Bs[buf][0] + c * 4096 + wid * 1024);
    }
  };

  const int wr  = (wid >> 1) * 64;
  const int wc  = (wid & 1) * 64;
  const int llo = lane & 15;
  const int lhi = lane >> 4;
  const int swz = (llo & 7) << 4;

  f32x4 acc[4][4];
#pragma unroll
  for (int i = 0; i < 4; ++i)
#pragma unroll
    for (int j = 0; j < 4; ++j) acc[i][j] = f32x4{0.f, 0.f, 0.f, 0.f};

  stage(0, 0);
  __syncthreads();

  for (int kt = 0; kt < ND / 64; ++kt) {
    const int cb = kt & 1;
    if (kt + 1 < ND / 64) stage(cb ^ 1, (kt + 1) * 64);
#pragma unroll
    for (int kk = 0; kk < 2; ++kk) {
      const int kb = (kk * 64 + lhi * 16) ^ swz;  // byte offset within 128B row
      short8 a[4], b[4];
#pragma unroll
      for (int i = 0; i < 4; ++i) {
        a[i] = *reinterpret_cast<const short8*>(
            (const char*)&As[cb][0] + (wr + i * 16 + llo) * 128 + kb);
        b[i] = *reinterpret_cast<const short8*>(
            (const char*)&Bs[cb][0] + (wc + i * 16 + llo) * 128 + kb);
      }
#pragma unroll
      for (int i = 0; i < 4; ++i)
#pragma unroll
        for (int j = 0; j < 4; ++j)
          acc[i][j] = __builtin_amdgcn_mfma_f32_16x16x32_bf16(a[i], b[j], acc[i][j], 0, 0, 0);
    }
    __syncthreads();
  }

  float bj[4];
#pragma unroll
  for (int j = 0; j < 4; ++j) bj[j] = bias[n0 + wc + j * 16 + llo];

#pragma unroll
  for (int i = 0; i < 4; ++i) {
#pragma unroll
    for (int reg = 0; reg < 4; ++reg) {
      const int orow = wr + i * 16 + lhi * 4 + reg;
      if (row0 + orow < cnt) {
        if (MODE == 0) {
          size_t rb = (size_t)br * NB * ND + (size_t)(off + row0 + orow) * ND + n0;
#pragma unroll
          for (int j = 0; j < 4; ++j)
            Hc[rb + wc + j * 16 + llo] = f2bf(ftanh(acc[i][j][reg] + bj[j]));
        } else {
          const int tok = meta[TLIST + off + row0 + orow];
          size_t rb = (size_t)br * NB * ND + (size_t)tok * ND + n0;
#pragma unroll
          for (int j = 0; j < 4; ++j)
            out[rb + wc + j * 16 + llo] = ftanh(acc[i][j][reg] + bj[j]);
        }
      }
    }
  }
}

// ================= legacy fallback (round-2 proven) =================
constexpr int LTM = 64;
constexpr int LTN = 64;
constexpr int LBKT = 64;
constexpr int LBKP = LBKT + 8;
constexpr int LNT = ND / LTN;
constexpr int LMT_CAP = NB / LTM + NG;

template<int MODE>
__global__ __launch_bounds__(256, 4) void mlp_gemm(
    const float* __restrict__ X,
    __hip_bfloat16* __restrict__ Hp,
    __hip_bfloat16* __restrict__ Hv,
    const float* __restrict__ Wp, const float* __restrict__ bp,
    const float* __restrict__ Wv, const float* __restrict__ bv,
    const int* __restrict__ meta,
    float* __restrict__ out)
{
  const int tileIdx = blockIdx.y;
  if (tileIdx >= meta[NTILES]) return;
  const int g   = meta[TILEG + tileIdx];
  const int mt  = meta[TILEM + tileIdx];
  const int off = meta[OFFS + g];
  const int cnt = meta[OFFS + g + 1] - off;
  const int row0 = mt * LTM;
  const int n0 = blockIdx.x * LTN;
  const int br = blockIdx.z;

  const float* Wt   = (br ? Wv : Wp) + (size_t)g * ND * ND;
  const float* bias = (br ? bv : bp) + (size_t)g * ND;

  __shared__ unsigned short As[2][LTM][LBKP];
  __shared__ unsigned short Bs[2][LTN][LBKP];

  const int t = threadIdx.x;
  const int r = t >> 2;
  const int q = t & 3;

  const int gr = row0 + r;
  const bool rowok = (gr < cnt);
  int tok = 0;
  if (MODE == 0) tok = rowok ? meta[TLIST + off + gr] : 0;
  const float* arow = X + (size_t)tok * ND;
  const __hip_bfloat16* Hin = br ? Hv : Hp;
  const unsigned short* hrow =
      (const unsigned short*)(Hin + (size_t)(off + (rowok ? gr : 0)) * ND);

  auto stage = [&](int buf, int k0) {
    if (MODE == 0) {
#pragma unroll
      for (int i = 0; i < 4; ++i) {
        int c = q * 16 + i * 4;
        float4 v = make_float4(0.f, 0.f, 0.f, 0.f);
        if (rowok) v = *reinterpret_cast<const float4*>(arow + k0 + c);
        ushort4 s;
        s.x = f2bf(v.x); s.y = f2bf(v.y); s.z = f2bf(v.z); s.w = f2bf(v.w);
        *reinterpret_cast<ushort4*>(&As[buf][r][c]) = s;
      }
    } else {
#pragma unroll
      for (int i = 0; i < 2; ++i) {
        int c = q * 16 + i * 8;
        int4 v = make_int4(0, 0, 0, 0);
        if (rowok) v = *reinterpret_cast<const int4*>(hrow + k0 + c);
        *reinterpret_cast<int4*>(&As[buf][r][c]) = v;
      }
    }
#pragma unroll
    for (int i = 0; i < 4; ++i) {
      int c = q * 16 + i * 4;
      float4 v = *reinterpret_cast<const float4*>(Wt + (size_t)(k0 + r) * ND + n0 + c);
      Bs[buf][c + 0][r] = f2bf(v.x);
      Bs[buf][c + 1][r] = f2bf(v.y);
      Bs[buf][c + 2][r] = f2bf(v.z);
      Bs[buf][c + 3][r] = f2bf(v.w);
    }
  };

  const int lane = t & 63;
  const int wid  = t >> 6;
  const int wr   = (wid >> 1) * 32;
  const int wc   = (wid & 1) * 32;
  const int lhi  = lane >> 4;
  const int llo  = lane & 15;

  f32x4 acc[2][2];
#pragma unroll
  for (int i = 0; i < 2; ++i)
#pragma unroll
    for (int j = 0; j < 2; ++j) acc[i][j] = f32x4{0.f, 0.f, 0.f, 0.f};

  stage(0, 0);
  __syncthreads();

  for (int kt = 0; kt < ND / LBKT; ++kt) {
    const int cb = kt & 1;
    if (kt + 1 < ND / LBKT) stage(cb ^ 1, (kt + 1) * LBKT);
#pragma unroll
    for (int kk = 0; kk < 2; ++kk) {
      int kb = kk * 32 + lhi * 8;
      short8 a0 = *reinterpret_cast<const short8*>(&As[cb][wr + llo][kb]);
      short8 a1 = *reinterpret_cast<const short8*>(&As[cb][wr + 16 + llo][kb]);
      short8 b0 = *reinterpret_cast<const short8*>(&Bs[cb][wc + llo][kb]);
      short8 b1 = *reinterpret_cast<const short8*>(&Bs[cb][wc + 16 + llo][kb]);
      acc[0][0] = __builtin_amdgcn_mfma_f32_16x16x32_bf16(a0, b0, acc[0][0], 0, 0, 0);
      acc[0][1] = __builtin_amdgcn_mfma_f32_16x16x32_bf16(a0, b1, acc[0][1], 0, 0, 0);
      acc[1][0] = __builtin_amdgcn_mfma_f32_16x16x32_bf16(a1, b0, acc[1][0], 0, 0, 0);
      acc[1][1] = __builtin_amdgcn_mfma_f32_16x16x32_bf16(a1, b1, acc[1][1], 0, 0, 0);
    }
    __syncthreads();
  }

  float bj0 = bias[n0 + wc + llo];
  float bj1 = bias[n0 + wc + 16 + llo];
  __hip_bfloat16* Hout = br ? Hv : Hp;
#pragma unroll
  for (int i = 0; i < 2; ++i) {
#pragma unroll
    for (int reg = 0; reg < 4; ++reg) {
      int m = wr + i * 16 + lhi * 4 + reg;
      int grr = row0 + m;
      if (grr < cnt) {
        float v0 = ftanh(acc[i][0][reg] + bj0);
        float v1 = ftanh(acc[i][1][reg] + bj1);
        if (MODE == 0) {
          size_t rowbase = (size_t)(off + grr) * ND + n0;
          Hout[rowbase + wc + llo]      = __float2bfloat16(v0);
          Hout[rowbase + wc + 16 + llo] = __float2bfloat16(v1);
        } else {
          int tok2 = meta[TLIST + off + grr];
          size_t rowbase = (size_t)br * NB * ND + (size_t)tok2 * ND + n0;
          out[rowbase + wc + llo]      = v0;
          out[rowbase + wc + 16 + llo] = v1;
        }
      }
    }
  }
}

extern "C" void kernel_launch(void* const* d_in, const int* in_sizes, int n_in,
                              void* d_out, int out_size, void* d_ws, size_t ws_size,
                              hipStream_t stream) {
  const float* features = (const float*)d_in[0];
  const float* Wp0 = (const float*)d_in[1];
  const float* bp0 = (const float*)d_in[2];
  const float* Wp1 = (const float*)d_in[3];
  const float* bp1 = (const float*)d_in[4];
  const float* Wv0 = (const float*)d_in[5];
  const float* bv0 = (const float*)d_in[6];
  const float* Wv1 = (const float*)d_in[7];
  const float* bv1 = (const float*)d_in[8];
  const int* goal  = (const int*)d_in[9];
  float* out = (float*)d_out;
  int* meta = (int*)d_ws;

  if (ws_size >= FAST_WS_NEED) {
    unsigned short* Xc = (unsigned short*)((char*)d_ws + XC_OFF);
    unsigned short* Hc = (unsigned short*)((char*)d_ws + HC_OFF);
    unsigned short* Wt = (unsigned short*)((char*)d_ws + WT_OFF);

    bin_k<<<1, 256, 0, stream>>>(goal, meta, 128);
    xc_k<<<NB / 4, 256, 0, stream>>>(features, meta, Xc);
    wt_k<<<4 * NG * 64, 256, 0, stream>>>(Wp0, Wv0, Wp1, Wv1, Wt);

    dim3 grid(ND / 128, NB / 128 + NG, 2);
    gemm_f<0><<<grid, 256, 0, stream>>>(Xc, Hc, Wt + 0 * WT_TENSOR, Wt + 1 * WT_TENSOR,
                                        bp0, bv0, meta, out);
    gemm_f<1><<<grid, 256, 0, stream>>>(Hc, Hc, Wt + 2 * WT_TENSOR, Wt + 3 * WT_TENSOR,
                                        bp1, bv1, meta, out);
  } else {
    __hip_bfloat16* Hp = (__hip_bfloat16*)((char*)d_ws + H_OFF);
    __hip_bfloat16* Hv = Hp + (size_t)NB * ND;

    bin_k<<<1, 256, 0, stream>>>(goal, meta, LTM);
    dim3 grid(LNT, LMT_CAP, 2);
    mlp_gemm<0><<<grid, 256, 0, stream>>>(features, Hp, Hv, Wp0, bp0, Wv0, bv0, meta, out);
    mlp_gemm<1><<<grid, 256, 0, stream>>>(features, Hp, Hv, Wp1, bp1, Wv1, bv1, meta, out);
  }
}

// Round 4
// 63.167 us; speedup vs baseline: 1.4154x; 1.1223x over previous
//
#include <hip/hip_runtime.h>
#include <hip/hip_bf16.h>

// Problem constants
constexpr int NG = 16;    // experts
constexpr int ND = 512;   // feature dim
constexpr int NB = 4096;  // batch
constexpr int DD = ND * ND;

typedef __attribute__((ext_vector_type(8))) short short8;
typedef __attribute__((ext_vector_type(4))) float f32x4;

// ---------------- meta layout in d_ws (ints) ----------------
constexpr int OFFS   = 0;    // 17 ints: per-expert offsets (exclusive scan) + total
constexpr int TILEG  = 32;   // tile -> expert
constexpr int TILEM  = 112;  // tile -> m-tile within expert
constexpr int NTILES = 192;  // 1 int
constexpr int TLIST  = 256;  // 4096 ints: compact pos -> token

constexpr size_t META_BYTES = 32768;
constexpr size_t HC_OFF = META_BYTES;                       // bf16 [2][4096][512] = 8 MB
constexpr size_t FAST_WS_NEED = HC_OFF + 2ull * NB * ND * 2;

// legacy ws layout
constexpr size_t H_OFF = 32768;

__device__ inline unsigned short f2bf(float f) {          // RNE (legacy path)
  union { float f; unsigned u; } a; a.f = f;
  unsigned u = a.u;
  return (unsigned short)((u + 0x7fffu + ((u >> 16) & 1u)) >> 16);
}

__device__ inline short f2bf_hw(float f) {                // native cvt (RNE) on gfx950
  __bf16 h = (__bf16)f;
  return __builtin_bit_cast(short, h);
}

__device__ inline float ftanh(float x) {
  float e = __expf(2.0f * x);
  return 1.0f - 2.0f * __builtin_amdgcn_rcpf(e + 1.0f);
}

__device__ inline void gld16(const void* g, void* lds) {
  __builtin_amdgcn_global_load_lds(
      (const __attribute__((address_space(1))) unsigned int*)g,
      (__attribute__((address_space(3))) unsigned int*)lds, 16, 0, 0);
}

// ---------------- binning ----------------
__global__ void bin_k(const int* __restrict__ goal, int* __restrict__ meta, int tm) {
  __shared__ int cnt[NG], cur[NG];
  const int t = threadIdx.x;
  if (t < NG) cnt[t] = 0;
  __syncthreads();
  for (int i = t; i < NB; i += 256) atomicAdd(&cnt[goal[i]], 1);
  __syncthreads();
  if (t == 0) {
    int s = 0, nt = 0;
    for (int g = 0; g < NG; ++g) {
      meta[OFFS + g] = s;
      cur[g] = s;
      int c = cnt[g];
      int mts = (c + tm - 1) / tm;
      for (int m = 0; m < mts; ++m) { meta[TILEG + nt] = g; meta[TILEM + nt] = m; ++nt; }
      s += c;
    }
    meta[OFFS + NG] = s;
    meta[NTILES] = nt;
  }
  __syncthreads();
  for (int i = t; i < NB; i += 256) {
    int gg = goal[i];
    int p = atomicAdd(&cur[gg], 1);
    meta[TLIST + p] = i;
  }
}

// ---------------- fused GEMM, direct f32 weights ----------------
// 128x128 tile, BK=64, 256 threads (4 waves, wave tile 64x64, 4x4 frags).
// B operand: W f32 [k][n] -> reg-stage convert -> Bs[n][k] bf16, XOR-swizzled.
// MODE 0: A = features f32 gathered by token -> reg-stage convert. Out: Hc bf16.
// MODE 1: A = Hc bf16 compact via global_load_lds (pre-swizzled src). Out: f32 scatter.
// blockIdx.z: 0 = pi, 1 = vf.
template<int MODE>
__global__ __launch_bounds__(256, 2) void gemm_d(
    const float* __restrict__ Xf,
    unsigned short* __restrict__ Hc,
    const float* __restrict__ Wp, const float* __restrict__ Wv,
    const float* __restrict__ bp, const float* __restrict__ bv,
    const int* __restrict__ meta,
    float* __restrict__ out)
{
  __shared__ unsigned short As[2][128 * 64];
  __shared__ unsigned short Bs[2][128 * 64];

  const int tileIdx = blockIdx.y;
  if (tileIdx >= meta[NTILES]) return;
  const int g    = meta[TILEG + tileIdx];
  const int mt   = meta[TILEM + tileIdx];
  const int off  = meta[OFFS + g];
  const int cnt  = meta[OFFS + g + 1] - off;
  const int row0 = mt * 128;
  const int n0   = blockIdx.x * 128;
  const int br   = blockIdx.z;

  const float* W    = (br ? Wv : Wp) + (size_t)g * DD;   // [k][n], n contiguous
  const float* bias = (br ? bv : bp) + (size_t)g * ND;

  const int t    = threadIdx.x;
  const int lane = t & 63;
  const int wid  = t >> 6;

  // ---- B staging geometry: thread owns one n column, 4 k-octets ----
  const int bn  = t & 127;     // n within tile
  const int bth = t >> 7;      // 0/1 selects even/odd octet pair
  const float* wcol = W + n0 + bn;
  const int bwb = bn * 128;    // Bs row byte base

  // ---- A staging geometry ----
  // MODE 0: thread owns k-octet ao, rows i*32 + (t>>3)
  const int ao = t & 7;
  int tokA[4];
  // MODE 1: gld_lds chunks (round-3 proven)
  const unsigned short* srcA1[4];
  bool okA1[4];
  const unsigned short* Ab = Hc + (size_t)br * NB * ND;  // MODE 1 input

  if (MODE == 0) {
#pragma unroll
    for (int i = 0; i < 4; ++i) {
      int r = i * 32 + (t >> 3);
      tokA[i] = (row0 + r < cnt) ? meta[TLIST + off + row0 + r] : meta[TLIST + off];
    }
  } else {
#pragma unroll
    for (int c = 0; c < 4; ++c) {
      int o = c * 4096 + wid * 1024 + lane * 16;
      int r = o >> 7, w = o & 127;
      int so = (w ^ ((r & 7) << 4)) >> 1;
      okA1[c]  = (row0 + r < cnt);
      srcA1[c] = Ab + (size_t)(off + (okA1[c] ? row0 + r : 0)) * ND + so;
    }
  }

  auto stageB = [&](int buf, int k0) {
    float v[4][8];
#pragma unroll
    for (int i = 0; i < 4; ++i) {
      const float* p = wcol + (size_t)(k0 + (i * 2 + bth) * 8) * ND;
#pragma unroll
      for (int j = 0; j < 8; ++j) v[i][j] = p[(size_t)j * ND];
    }
#pragma unroll
    for (int i = 0; i < 4; ++i) {
      const int oct = i * 2 + bth;
      short8 o;
#pragma unroll
      for (int j = 0; j < 8; ++j) o[j] = f2bf_hw(v[i][j]);
      *reinterpret_cast<short8*>(
          (char*)&Bs[buf][0] + bwb + ((oct * 16) ^ ((bn & 7) << 4))) = o;
    }
  };

  auto stageA0 = [&](int buf, int k0) {
    float4 va[4], vb[4];
#pragma unroll
    for (int i = 0; i < 4; ++i) {
      const float* p = Xf + (size_t)tokA[i] * ND + k0 + ao * 8;
      va[i] = *reinterpret_cast<const float4*>(p);
      vb[i] = *reinterpret_cast<const float4*>(p + 4);
    }
#pragma unroll
    for (int i = 0; i < 4; ++i) {
      const int r = i * 32 + (t >> 3);
      short8 o;
      o[0] = f2bf_hw(va[i].x); o[1] = f2bf_hw(va[i].y);
      o[2] = f2bf_hw(va[i].z); o[3] = f2bf_hw(va[i].w);
      o[4] = f2bf_hw(vb[i].x); o[5] = f2bf_hw(vb[i].y);
      o[6] = f2bf_hw(vb[i].z); o[7] = f2bf_hw(vb[i].w);
      *reinterpret_cast<short8*>(
          (char*)&As[buf][0] + r * 128 + ((ao * 16) ^ ((r & 7) << 4))) = o;
    }
  };

  auto stageA1 = [&](int buf, int k0) {
#pragma unroll
    for (int c = 0; c < 4; ++c) {
      if (okA1[c])
        gld16(srcA1[c] + k0, (char*)&As[buf][0] + c * 4096 + wid * 1024);
    }
  };

  auto stage = [&](int buf, int k0) {
    if (MODE == 0) stageA0(buf, k0); else stageA1(buf, k0);
    stageB(buf, k0);
  };

  const int wr  = (wid >> 1) * 64;
  const int wc  = (wid & 1) * 64;
  const int llo = lane & 15;
  const int lhi = lane >> 4;
  const int swz = (llo & 7) << 4;

  f32x4 acc[4][4];
#pragma unroll
  for (int i = 0; i < 4; ++i)
#pragma unroll
    for (int j = 0; j < 4; ++j) acc[i][j] = f32x4{0.f, 0.f, 0.f, 0.f};

  stage(0, 0);
  __syncthreads();

  for (int kt = 0; kt < ND / 64; ++kt) {
    const int cb = kt & 1;
    if (kt + 1 < ND / 64) stage(cb ^ 1, (kt + 1) * 64);
#pragma unroll
    for (int kk = 0; kk < 2; ++kk) {
      const int kb = (kk * 64 + lhi * 16) ^ swz;  // byte offset within 128B row
      short8 a[4], b[4];
#pragma unroll
      for (int i = 0; i < 4; ++i) {
        a[i] = *reinterpret_cast<const short8*>(
            (const char*)&As[cb][0] + (wr + i * 16 + llo) * 128 + kb);
        b[i] = *reinterpret_cast<const short8*>(
            (const char*)&Bs[cb][0] + (wc + i * 16 + llo) * 128 + kb);
      }
#pragma unroll
      for (int i = 0; i < 4; ++i)
#pragma unroll
        for (int j = 0; j < 4; ++j)
          acc[i][j] = __builtin_amdgcn_mfma_f32_16x16x32_bf16(a[i], b[j], acc[i][j], 0, 0, 0);
    }
    __syncthreads();
  }

  float bj[4];
#pragma unroll
  for (int j = 0; j < 4; ++j) bj[j] = bias[n0 + wc + j * 16 + llo];

#pragma unroll
  for (int i = 0; i < 4; ++i) {
#pragma unroll
    for (int reg = 0; reg < 4; ++reg) {
      const int orow = wr + i * 16 + lhi * 4 + reg;
      if (row0 + orow < cnt) {
        if (MODE == 0) {
          size_t rb = (size_t)br * NB * ND + (size_t)(off + row0 + orow) * ND + n0;
#pragma unroll
          for (int j = 0; j < 4; ++j)
            Hc[rb + wc + j * 16 + llo] =
                (unsigned short)f2bf_hw(ftanh(acc[i][j][reg] + bj[j]));
        } else {
          const int tok = meta[TLIST + off + row0 + orow];
          size_t rb = (size_t)br * NB * ND + (size_t)tok * ND + n0;
#pragma unroll
          for (int j = 0; j < 4; ++j)
            out[rb + wc + j * 16 + llo] = ftanh(acc[i][j][reg] + bj[j]);
        }
      }
    }
  }
}

// ================= legacy fallback (round-2 proven) =================
constexpr int LTM = 64;
constexpr int LTN = 64;
constexpr int LBKT = 64;
constexpr int LBKP = LBKT + 8;
constexpr int LNT = ND / LTN;
constexpr int LMT_CAP = NB / LTM + NG;

template<int MODE>
__global__ __launch_bounds__(256, 4) void mlp_gemm(
    const float* __restrict__ X,
    __hip_bfloat16* __restrict__ Hp,
    __hip_bfloat16* __restrict__ Hv,
    const float* __restrict__ Wp, const float* __restrict__ bp,
    const float* __restrict__ Wv, const float* __restrict__ bv,
    const int* __restrict__ meta,
    float* __restrict__ out)
{
  const int tileIdx = blockIdx.y;
  if (tileIdx >= meta[NTILES]) return;
  const int g   = meta[TILEG + tileIdx];
  const int mt  = meta[TILEM + tileIdx];
  const int off = meta[OFFS + g];
  const int cnt = meta[OFFS + g + 1] - off;
  const int row0 = mt * LTM;
  const int n0 = blockIdx.x * LTN;
  const int br = blockIdx.z;

  const float* Wt   = (br ? Wv : Wp) + (size_t)g * DD;
  const float* bias = (br ? bv : bp) + (size_t)g * ND;

  __shared__ unsigned short As[2][LTM][LBKP];
  __shared__ unsigned short Bs[2][LTN][LBKP];

  const int t = threadIdx.x;
  const int r = t >> 2;
  const int q = t & 3;

  const int gr = row0 + r;
  const bool rowok = (gr < cnt);
  int tok = 0;
  if (MODE == 0) tok = rowok ? meta[TLIST + off + gr] : 0;
  const float* arow = X + (size_t)tok * ND;
  const __hip_bfloat16* Hin = br ? Hv : Hp;
  const unsigned short* hrow =
      (const unsigned short*)(Hin + (size_t)(off + (rowok ? gr : 0)) * ND);

  auto stage = [&](int buf, int k0) {
    if (MODE == 0) {
#pragma unroll
      for (int i = 0; i < 4; ++i) {
        int c = q * 16 + i * 4;
        float4 v = make_float4(0.f, 0.f, 0.f, 0.f);
        if (rowok) v = *reinterpret_cast<const float4*>(arow + k0 + c);
        ushort4 s;
        s.x = f2bf(v.x); s.y = f2bf(v.y); s.z = f2bf(v.z); s.w = f2bf(v.w);
        *reinterpret_cast<ushort4*>(&As[buf][r][c]) = s;
      }
    } else {
#pragma unroll
      for (int i = 0; i < 2; ++i) {
        int c = q * 16 + i * 8;
        int4 v = make_int4(0, 0, 0, 0);
        if (rowok) v = *reinterpret_cast<const int4*>(hrow + k0 + c);
        *reinterpret_cast<int4*>(&As[buf][r][c]) = v;
      }
    }
#pragma unroll
    for (int i = 0; i < 4; ++i) {
      int c = q * 16 + i * 4;
      float4 v = *reinterpret_cast<const float4*>(Wt + (size_t)(k0 + r) * ND + n0 + c);
      Bs[buf][c + 0][r] = f2bf(v.x);
      Bs[buf][c + 1][r] = f2bf(v.y);
      Bs[buf][c + 2][r] = f2bf(v.z);
      Bs[buf][c + 3][r] = f2bf(v.w);
    }
  };

  const int lane = t & 63;
  const int wid  = t >> 6;
  const int wr   = (wid >> 1) * 32;
  const int wc   = (wid & 1) * 32;
  const int lhi  = lane >> 4;
  const int llo  = lane & 15;

  f32x4 acc[2][2];
#pragma unroll
  for (int i = 0; i < 2; ++i)
#pragma unroll
    for (int j = 0; j < 2; ++j) acc[i][j] = f32x4{0.f, 0.f, 0.f, 0.f};

  stage(0, 0);
  __syncthreads();

  for (int kt = 0; kt < ND / LBKT; ++kt) {
    const int cb = kt & 1;
    if (kt + 1 < ND / LBKT) stage(cb ^ 1, (kt + 1) * LBKT);
#pragma unroll
    for (int kk = 0; kk < 2; ++kk) {
      int kb = kk * 32 + lhi * 8;
      short8 a0 = *reinterpret_cast<const short8*>(&As[cb][wr + llo][kb]);
      short8 a1 = *reinterpret_cast<const short8*>(&As[cb][wr + 16 + llo][kb]);
      short8 b0 = *reinterpret_cast<const short8*>(&Bs[cb][wc + llo][kb]);
      short8 b1 = *reinterpret_cast<const short8*>(&Bs[cb][wc + 16 + llo][kb]);
      acc[0][0] = __builtin_amdgcn_mfma_f32_16x16x32_bf16(a0, b0, acc[0][0], 0, 0, 0);
      acc[0][1] = __builtin_amdgcn_mfma_f32_16x16x32_bf16(a0, b1, acc[0][1], 0, 0, 0);
      acc[1][0] = __builtin_amdgcn_mfma_f32_16x16x32_bf16(a1, b0, acc[1][0], 0, 0, 0);
      acc[1][1] = __builtin_amdgcn_mfma_f32_16x16x32_bf16(a1, b1, acc[1][1], 0, 0, 0);
    }
    __syncthreads();
  }

  float bj0 = bias[n0 + wc + llo];
  float bj1 = bias[n0 + wc + 16 + llo];
  __hip_bfloat16* Hout = br ? Hv : Hp;
#pragma unroll
  for (int i = 0; i < 2; ++i) {
#pragma unroll
    for (int reg = 0; reg < 4; ++reg) {
      int m = wr + i * 16 + lhi * 4 + reg;
      int grr = row0 + m;
      if (grr < cnt) {
        float v0 = ftanh(acc[i][0][reg] + bj0);
        float v1 = ftanh(acc[i][1][reg] + bj1);
        if (MODE == 0) {
          size_t rowbase = (size_t)(off + grr) * ND + n0;
          Hout[rowbase + wc + llo]      = __float2bfloat16(v0);
          Hout[rowbase + wc + 16 + llo] = __float2bfloat16(v1);
        } else {
          int tok2 = meta[TLIST + off + grr];
          size_t rowbase = (size_t)br * NB * ND + (size_t)tok2 * ND + n0;
          out[rowbase + wc + llo]      = v0;
          out[rowbase + wc + 16 + llo] = v1;
        }
      }
    }
  }
}

extern "C" void kernel_launch(void* const* d_in, const int* in_sizes, int n_in,
                              void* d_out, int out_size, void* d_ws, size_t ws_size,
                              hipStream_t stream) {
  const float* features = (const float*)d_in[0];
  const float* Wp0 = (const float*)d_in[1];
  const float* bp0 = (const float*)d_in[2];
  const float* Wp1 = (const float*)d_in[3];
  const float* bp1 = (const float*)d_in[4];
  const float* Wv0 = (const float*)d_in[5];
  const float* bv0 = (const float*)d_in[6];
  const float* Wv1 = (const float*)d_in[7];
  const float* bv1 = (const float*)d_in[8];
  const int* goal  = (const int*)d_in[9];
  float* out = (float*)d_out;
  int* meta = (int*)d_ws;

  if (ws_size >= FAST_WS_NEED) {
    unsigned short* Hc = (unsigned short*)((char*)d_ws + HC_OFF);

    bin_k<<<1, 256, 0, stream>>>(goal, meta, 128);

    dim3 grid(ND / 128, NB / 128 + NG, 2);
    gemm_d<0><<<grid, 256, 0, stream>>>(features, Hc, Wp0, Wv0, bp0, bv0, meta, out);
    gemm_d<1><<<grid, 256, 0, stream>>>(features, Hc, Wp1, Wv1, bp1, bv1, meta, out);
  } else {
    __hip_bfloat16* Hp = (__hip_bfloat16*)((char*)d_ws + H_OFF);
    __hip_bfloat16* Hv = Hp + (size_t)NB * ND;

    bin_k<<<1, 256, 0, stream>>>(goal, meta, LTM);
    dim3 grid(LNT, LMT_CAP, 2);
    mlp_gemm<0><<<grid, 256, 0, stream>>>(features, Hp, Hv, Wp0, bp0, Wv0, bv0, meta, out);
    mlp_gemm<1><<<grid, 256, 0, stream>>>(features, Hp, Hv, Wp1, bp1, Wv1, bv1, meta, out);
  }
}

// Round 6
// 61.188 us; speedup vs baseline: 1.4612x; 1.0323x over previous
//
#include <hip/hip_runtime.h>
#include <hip/hip_bf16.h>

// Problem constants
constexpr int NG = 16;    // experts
constexpr int ND = 512;   // feature dim
constexpr int NB = 4096;  // batch
constexpr int DD = ND * ND;

typedef __attribute__((ext_vector_type(8))) short short8;
typedef __attribute__((ext_vector_type(4))) short short4v;
typedef __attribute__((ext_vector_type(4))) float f32x4;

// ---------------- meta layout in d_ws (ints) ----------------
constexpr int OFFS   = 0;    // 17 ints: per-expert offsets + total
constexpr int TILEG  = 32;   // tile -> expert
constexpr int TILEM  = 112;  // tile -> m-tile within expert
constexpr int NTILES = 192;  // 1 int
constexpr int TLIST  = 256;  // 4096 ints: compact pos -> token

constexpr size_t META_BYTES = 32768;
constexpr size_t XC_OFF = META_BYTES;                    // bf16 [4096][512] = 4 MB
constexpr size_t HC_OFF = XC_OFF + (size_t)NB * ND * 2;  // bf16 [2][4096][512] = 8 MB
constexpr size_t FAST_WS_NEED = HC_OFF + 2ull * NB * ND * 2;

// legacy ws layout
constexpr size_t H_OFF = 32768;

__device__ inline unsigned short f2bf(float f) {          // RNE (legacy path)
  union { float f; unsigned u; } a; a.f = f;
  unsigned u = a.u;
  return (unsigned short)((u + 0x7fffu + ((u >> 16) & 1u)) >> 16);
}

__device__ inline short f2bf_hw(float f) {                // native cvt (RNE)
  __bf16 h = (__bf16)f;
  return __builtin_bit_cast(short, h);
}

__device__ inline float ftanh(float x) {
  float e = __expf(2.0f * x);
  return 1.0f - 2.0f * __builtin_amdgcn_rcpf(e + 1.0f);
}

__device__ inline void gld16(const void* g, void* lds) {
  __builtin_amdgcn_global_load_lds(
      (const __attribute__((address_space(1))) unsigned int*)g,
      (__attribute__((address_space(3))) unsigned int*)lds, 16, 0, 0);
}

__device__ inline unsigned lds_off(const void* p) {
  return (unsigned)(size_t)(const __attribute__((address_space(3))) char*)p;
}

#define DS128(d, a, OFF) \
  asm volatile("ds_read_b128 %0, %1 offset:%c2" : "=v"(d) : "v"(a), "i"(OFF) : "memory")
#define TRB16(d, a, OFF) \
  asm volatile("ds_read_b64_tr_b16 %0, %1 offset:%c2" : "=v"(d) : "v"(a), "i"(OFF) : "memory")

// ---------------- binning ----------------
__global__ void bin_k(const int* __restrict__ goal, int* __restrict__ meta, int tm) {
  __shared__ int cnt[NG], cur[NG];
  const int t = threadIdx.x;
  if (t < NG) cnt[t] = 0;
  __syncthreads();
  for (int i = t; i < NB; i += 256) atomicAdd(&cnt[goal[i]], 1);
  __syncthreads();
  if (t == 0) {
    int s = 0, nt = 0;
    for (int g = 0; g < NG; ++g) {
      meta[OFFS + g] = s;
      cur[g] = s;
      int c = cnt[g];
      int mts = (c + tm - 1) / tm;
      for (int m = 0; m < mts; ++m) { meta[TILEG + nt] = g; meta[TILEM + nt] = m; ++nt; }
      s += c;
    }
    meta[OFFS + NG] = s;
    meta[NTILES] = nt;
  }
  __syncthreads();
  for (int i = t; i < NB; i += 256) {
    int gg = goal[i];
    int p = atomicAdd(&cur[gg], 1);
    meta[TLIST + p] = i;
  }
}

// ---------------- gather+convert features -> compact bf16 ----------------
__global__ void xc_k(const float* __restrict__ X, const int* __restrict__ meta,
                     unsigned short* __restrict__ Xc) {
  const int t = threadIdx.x;
  const int pos  = blockIdx.x * 4 + (t >> 6);
  const int lane = t & 63;
  const int tok = meta[TLIST + pos];
  const float* src = X + (size_t)tok * ND + lane * 8;
  float4 a = *reinterpret_cast<const float4*>(src);
  float4 b = *reinterpret_cast<const float4*>(src + 4);
  short8 o;
  o[0] = f2bf_hw(a.x); o[1] = f2bf_hw(a.y); o[2] = f2bf_hw(a.z); o[3] = f2bf_hw(a.w);
  o[4] = f2bf_hw(b.x); o[5] = f2bf_hw(b.y); o[6] = f2bf_hw(b.z); o[7] = f2bf_hw(b.w);
  *reinterpret_cast<short8*>(Xc + (size_t)pos * ND + lane * 8) = o;
}

// ---------------- fused GEMM: 128m x 64n tile, BK=64 ----------------
// A: bf16 compact rows via global_load_lds (pre-swizzled source, linear LDS dest).
// B: W f32 [k][n] -> coalesced row loads -> cvt -> subtiled LDS [k/4][n/16][4][16]
//    -> ds_read_b64_tr_b16 delivers k-minor fragments.
//    tr_b16 model (m156/m162-consistent): tile base = addr & ~127; column = addr
//    bits[6:3]; lane gets bytes base + col*2 + j*32 (4x16 bf16 row-major tile).
// MODE 0: A = Xc, out -> Hc bf16 (tanh). MODE 1: A = Hc, out -> f32 scatter (tanh).
template<int MODE>
__global__ __launch_bounds__(256, 3) void gemm_t(
    const unsigned short* __restrict__ Abase,
    unsigned short* __restrict__ Hc,
    const float* __restrict__ Wp, const float* __restrict__ Wv,
    const float* __restrict__ bp, const float* __restrict__ bv,
    const int* __restrict__ meta,
    float* __restrict__ out)
{
  __shared__ __attribute__((aligned(128))) unsigned short As[2][128 * 64];
  __shared__ __attribute__((aligned(128))) unsigned short Bs[2][64 * 64];

  const int tileIdx = blockIdx.y;
  if (tileIdx >= meta[NTILES]) return;
  const int g    = meta[TILEG + tileIdx];
  const int mt   = meta[TILEM + tileIdx];
  const int off  = meta[OFFS + g];
  const int cnt  = meta[OFFS + g + 1] - off;
  const int row0 = mt * 128;
  const int n0   = blockIdx.x * 64;
  const int br   = blockIdx.z;

  const float* W    = (br ? Wv : Wp) + (size_t)g * DD;
  const float* bias = (br ? bv : bp) + (size_t)g * ND;
  const unsigned short* Ab = Abase + (MODE == 1 ? (size_t)br * NB * ND : 0);

  const int t    = threadIdx.x;
  const int lane = t & 63;
  const int wid  = t >> 6;

  // ---- A staging: gld16, 4 chunks, source pre-swizzled ----
  const unsigned short* srcA[4];
  bool okA[4];
#pragma unroll
  for (int c = 0; c < 4; ++c) {
    int o = c * 4096 + wid * 1024 + lane * 16;
    int r = o >> 7, w = o & 127;
    int so = (w ^ ((r & 7) << 4)) >> 1;
    okA[c]  = (row0 + r < cnt);
    srcA[c] = Ab + (size_t)(off + (okA[c] ? row0 + r : 0)) * ND + so;
  }

  // ---- B staging: thread covers rows kb, kb+32, cols co*8..+7 ----
  const int kb = t >> 3;    // 0..31
  const int co = t & 7;     // 0..7
  float rB[16];

  auto loadB = [&](int k0) {
#pragma unroll
    for (int h = 0; h < 2; ++h) {
      const float* p = W + (size_t)(k0 + kb + h * 32) * ND + n0 + co * 8;
      *reinterpret_cast<float4*>(&rB[h * 8])     = *reinterpret_cast<const float4*>(p);
      *reinterpret_cast<float4*>(&rB[h * 8 + 4]) = *reinterpret_cast<const float4*>(p + 4);
    }
  };
  auto writeB = [&](int buf) {
#pragma unroll
    for (int h = 0; h < 2; ++h) {
      const int k = kb + h * 32;
      short8 o;
#pragma unroll
      for (int j = 0; j < 8; ++j) o[j] = f2bf_hw(rB[h * 8 + j]);
      *reinterpret_cast<short8*>(
          (char*)&Bs[buf][0] + ((k >> 2) * 4 + (co >> 1)) * 128 + (k & 3) * 32 + (co & 1) * 16) = o;
    }
  };
  auto loadA = [&](int buf, int k0) {
    char* dst = (char*)&As[buf][0];
#pragma unroll
    for (int c = 0; c < 4; ++c)
      if (okA[c]) gld16(srcA[c] + k0, dst + c * 4096 + wid * 1024);
  };

  // ---- wave compute geometry ----
  const int wr  = (wid >> 1) * 64;
  const int wc  = (wid & 1) * 32;
  const int llo = lane & 15;
  const int lhi = lane >> 4;
  const int swz = (llo & 7) << 4;
  const unsigned c0 = (unsigned)((lhi * 16) ^ swz);
  const unsigned c1 = (unsigned)((64 + lhi * 16) ^ swz);
  const unsigned aAddr0 = lds_off(&As[0][0]) + (wr + llo) * 128;
  // column select = addr bits[6:3] -> llo*8 (FIX: was llo*2)
  const unsigned bAddr0 = lds_off(&Bs[0][0]) + lhi * 1024 + (wc >> 4) * 128 + llo * 8;

  f32x4 acc[4][2];
#pragma unroll
  for (int i = 0; i < 4; ++i)
#pragma unroll
    for (int j = 0; j < 2; ++j) acc[i][j] = f32x4{0.f, 0.f, 0.f, 0.f};

  // prologue: fill buf 0
  loadA(0, 0);
  loadB(0);
  writeB(0);
  __syncthreads();

  for (int kt = 0; kt < 8; ++kt) {
    const int cb = kt & 1;
    const unsigned aOff = (unsigned)cb * 16384u;
    const unsigned bOff = (unsigned)cb * 8192u;
    if (kt < 7) {             // issue next-tile loads early (T14)
      loadA(cb ^ 1, (kt + 1) * 64);
      loadB((kt + 1) * 64);
    }
#pragma unroll
    for (int kk = 0; kk < 2; ++kk) {
      const unsigned aA = aAddr0 + aOff + (kk ? c1 : c0);
      const unsigned bA = bAddr0 + bOff;
      short8 a0, a1, a2, a3;
      short4v t00, t01, t10, t11;
      DS128(a0, aA, 0);
      DS128(a1, aA, 2048);
      DS128(a2, aA, 4096);
      DS128(a3, aA, 6144);
      if (kk == 0) {
        TRB16(t00, bA, 0);    TRB16(t01, bA, 512);
        TRB16(t10, bA, 128);  TRB16(t11, bA, 640);
      } else {
        TRB16(t00, bA, 4096); TRB16(t01, bA, 4608);
        TRB16(t10, bA, 4224); TRB16(t11, bA, 4736);
      }
      asm volatile("s_waitcnt lgkmcnt(0)" ::: "memory");
      __builtin_amdgcn_sched_barrier(0);
      short8 b0 = __builtin_shufflevector(t00, t01, 0, 1, 2, 3, 4, 5, 6, 7);
      short8 b1 = __builtin_shufflevector(t10, t11, 0, 1, 2, 3, 4, 5, 6, 7);
      acc[0][0] = __builtin_amdgcn_mfma_f32_16x16x32_bf16(a0, b0, acc[0][0], 0, 0, 0);
      acc[0][1] = __builtin_amdgcn_mfma_f32_16x16x32_bf16(a0, b1, acc[0][1], 0, 0, 0);
      acc[1][0] = __builtin_amdgcn_mfma_f32_16x16x32_bf16(a1, b0, acc[1][0], 0, 0, 0);
      acc[1][1] = __builtin_amdgcn_mfma_f32_16x16x32_bf16(a1, b1, acc[1][1], 0, 0, 0);
      acc[2][0] = __builtin_amdgcn_mfma_f32_16x16x32_bf16(a2, b0, acc[2][0], 0, 0, 0);
      acc[2][1] = __builtin_amdgcn_mfma_f32_16x16x32_bf16(a2, b1, acc[2][1], 0, 0, 0);
      acc[3][0] = __builtin_amdgcn_mfma_f32_16x16x32_bf16(a3, b0, acc[3][0], 0, 0, 0);
      acc[3][1] = __builtin_amdgcn_mfma_f32_16x16x32_bf16(a3, b1, acc[3][1], 0, 0, 0);
    }
    if (kt < 7) {
      writeB(cb ^ 1);
      __syncthreads();
    }
  }

  // epilogue: bias + tanh + store
  float bj[2];
#pragma unroll
  for (int j = 0; j < 2; ++j) bj[j] = bias[n0 + wc + j * 16 + llo];

#pragma unroll
  for (int i = 0; i < 4; ++i) {
#pragma unroll
    for (int reg = 0; reg < 4; ++reg) {
      const int orow = wr + i * 16 + lhi * 4 + reg;
      if (row0 + orow < cnt) {
        if (MODE == 0) {
          size_t rb = (size_t)br * NB * ND + (size_t)(off + row0 + orow) * ND + n0;
#pragma unroll
          for (int j = 0; j < 2; ++j)
            Hc[rb + wc + j * 16 + llo] =
                (unsigned short)f2bf_hw(ftanh(acc[i][j][reg] + bj[j]));
        } else {
          const int tok = meta[TLIST + off + row0 + orow];
          size_t rb = (size_t)br * NB * ND + (size_t)tok * ND + n0;
#pragma unroll
          for (int j = 0; j < 2; ++j)
            out[rb + wc + j * 16 + llo] = ftanh(acc[i][j][reg] + bj[j]);
        }
      }
    }
  }
}

// ================= legacy fallback (round-2 proven) =================
constexpr int LTM = 64;
constexpr int LTN = 64;
constexpr int LBKT = 64;
constexpr int LBKP = LBKT + 8;
constexpr int LNT = ND / LTN;
constexpr int LMT_CAP = NB / LTM + NG;

template<int MODE>
__global__ __launch_bounds__(256, 4) void mlp_gemm(
    const float* __restrict__ X,
    __hip_bfloat16* __restrict__ Hp,
    __hip_bfloat16* __restrict__ Hv,
    const float* __restrict__ Wp, const float* __restrict__ bp,
    const float* __restrict__ Wv, const float* __restrict__ bv,
    const int* __restrict__ meta,
    float* __restrict__ out)
{
  const int tileIdx = blockIdx.y;
  if (tileIdx >= meta[NTILES]) return;
  const int g   = meta[TILEG + tileIdx];
  const int mt  = meta[TILEM + tileIdx];
  const int off = meta[OFFS + g];
  const int cnt = meta[OFFS + g + 1] - off;
  const int row0 = mt * LTM;
  const int n0 = blockIdx.x * LTN;
  const int br = blockIdx.z;

  const float* Wt   = (br ? Wv : Wp) + (size_t)g * DD;
  const float* bias = (br ? bv : bp) + (size_t)g * ND;

  __shared__ unsigned short As[2][LTM][LBKP];
  __shared__ unsigned short Bs[2][LTN][LBKP];

  const int t = threadIdx.x;
  const int r = t >> 2;
  const int q = t & 3;

  const int gr = row0 + r;
  const bool rowok = (gr < cnt);
  int tok = 0;
  if (MODE == 0) tok = rowok ? meta[TLIST + off + gr] : 0;
  const float* arow = X + (size_t)tok * ND;
  const __hip_bfloat16* Hin = br ? Hv : Hp;
  const unsigned short* hrow =
      (const unsigned short*)(Hin + (size_t)(off + (rowok ? gr : 0)) * ND);

  auto stage = [&](int buf, int k0) {
    if (MODE == 0) {
#pragma unroll
      for (int i = 0; i < 4; ++i) {
        int c = q * 16 + i * 4;
        float4 v = make_float4(0.f, 0.f, 0.f, 0.f);
        if (rowok) v = *reinterpret_cast<const float4*>(arow + k0 + c);
        ushort4 s;
        s.x = f2bf(v.x); s.y = f2bf(v.y); s.z = f2bf(v.z); s.w = f2bf(v.w);
        *reinterpret_cast<ushort4*>(&As[buf][r][c]) = s;
      }
    } else {
#pragma unroll
      for (int i = 0; i < 2; ++i) {
        int c = q * 16 + i * 8;
        int4 v = make_int4(0, 0, 0, 0);
        if (rowok) v = *reinterpret_cast<const int4*>(hrow + k0 + c);
        *reinterpret_cast<int4*>(&As[buf][r][c]) = v;
      }
    }
#pragma unroll
    for (int i = 0; i < 4; ++i) {
      int c = q * 16 + i * 4;
      float4 v = *reinterpret_cast<const float4*>(Wt + (size_t)(k0 + r) * ND + n0 + c);
      Bs[buf][c + 0][r] = f2bf(v.x);
      Bs[buf][c + 1][r] = f2bf(v.y);
      Bs[buf][c + 2][r] = f2bf(v.z);
      Bs[buf][c + 3][r] = f2bf(v.w);
    }
  };

  const int lane = t & 63;
  const int wid  = t >> 6;
  const int wr   = (wid >> 1) * 32;
  const int wc   = (wid & 1) * 32;
  const int lhi  = lane >> 4;
  const int llo  = lane & 15;

  f32x4 acc[2][2];
#pragma unroll
  for (int i = 0; i < 2; ++i)
#pragma unroll
    for (int j = 0; j < 2; ++j) acc[i][j] = f32x4{0.f, 0.f, 0.f, 0.f};

  stage(0, 0);
  __syncthreads();

  for (int kt = 0; kt < ND / LBKT; ++kt) {
    const int cb = kt & 1;
    if (kt + 1 < ND / LBKT) stage(cb ^ 1, (kt + 1) * LBKT);
#pragma unroll
    for (int kk = 0; kk < 2; ++kk) {
      int kbb = kk * 32 + lhi * 8;
      short8 a0 = *reinterpret_cast<const short8*>(&As[cb][wr + llo][kbb]);
      short8 a1 = *reinterpret_cast<const short8*>(&As[cb][wr + 16 + llo][kbb]);
      short8 b0 = *reinterpret_cast<const short8*>(&Bs[cb][wc + llo][kbb]);
      short8 b1 = *reinterpret_cast<const short8*>(&Bs[cb][wc + 16 + llo][kbb]);
      acc[0][0] = __builtin_amdgcn_mfma_f32_16x16x32_bf16(a0, b0, acc[0][0], 0, 0, 0);
      acc[0][1] = __builtin_amdgcn_mfma_f32_16x16x32_bf16(a0, b1, acc[0][1], 0, 0, 0);
      acc[1][0] = __builtin_amdgcn_mfma_f32_16x16x32_bf16(a1, b0, acc[1][0], 0, 0, 0);
      acc[1][1] = __builtin_amdgcn_mfma_f32_16x16x32_bf16(a1, b1, acc[1][1], 0, 0, 0);
    }
    __syncthreads();
  }

  float bj0 = bias[n0 + wc + llo];
  float bj1 = bias[n0 + wc + 16 + llo];
  __hip_bfloat16* Hout = br ? Hv : Hp;
#pragma unroll
  for (int i = 0; i < 2; ++i) {
#pragma unroll
    for (int reg = 0; reg < 4; ++reg) {
      int m = wr + i * 16 + lhi * 4 + reg;
      int grr = row0 + m;
      if (grr < cnt) {
        float v0 = ftanh(acc[i][0][reg] + bj0);
        float v1 = ftanh(acc[i][1][reg] + bj1);
        if (MODE == 0) {
          size_t rowbase = (size_t)(off + grr) * ND + n0;
          Hout[rowbase + wc + llo]      = __float2bfloat16(v0);
          Hout[rowbase + wc + 16 + llo] = __float2bfloat16(v1);
        } else {
          int tok2 = meta[TLIST + off + grr];
          size_t rowbase = (size_t)br * NB * ND + (size_t)tok2 * ND + n0;
          out[rowbase + wc + llo]      = v0;
          out[rowbase + wc + 16 + llo] = v1;
        }
      }
    }
  }
}

extern "C" void kernel_launch(void* const* d_in, const int* in_sizes, int n_in,
                              void* d_out, int out_size, void* d_ws, size_t ws_size,
                              hipStream_t stream) {
  const float* features = (const float*)d_in[0];
  const float* Wp0 = (const float*)d_in[1];
  const float* bp0 = (const float*)d_in[2];
  const float* Wp1 = (const float*)d_in[3];
  const float* bp1 = (const float*)d_in[4];
  const float* Wv0 = (const float*)d_in[5];
  const float* bv0 = (const float*)d_in[6];
  const float* Wv1 = (const float*)d_in[7];
  const float* bv1 = (const float*)d_in[8];
  const int* goal  = (const int*)d_in[9];
  float* out = (float*)d_out;
  int* meta = (int*)d_ws;

  if (ws_size >= FAST_WS_NEED) {
    unsigned short* Xc = (unsigned short*)((char*)d_ws + XC_OFF);
    unsigned short* Hc = (unsigned short*)((char*)d_ws + HC_OFF);

    bin_k<<<1, 256, 0, stream>>>(goal, meta, 128);
    xc_k<<<NB / 4, 256, 0, stream>>>(features, meta, Xc);

    dim3 grid(ND / 64, NB / 128 + NG, 2);
    gemm_t<0><<<grid, 256, 0, stream>>>(Xc, Hc, Wp0, Wv0, bp0, bv0, meta, out);
    gemm_t<1><<<grid, 256, 0, stream>>>(Hc, Hc, Wp1, Wv1, bp1, bv1, meta, out);
  } else {
    __hip_bfloat16* Hp = (__hip_bfloat16*)((char*)d_ws + H_OFF);
    __hip_bfloat16* Hv = Hp + (size_t)NB * ND;

    bin_k<<<1, 256, 0, stream>>>(goal, meta, LTM);
    dim3 grid(LNT, LMT_CAP, 2);
    mlp_gemm<0><<<grid, 256, 0, stream>>>(features, Hp, Hv, Wp0, bp0, Wv0, bv0, meta, out);
    mlp_gemm<1><<<grid, 256, 0, stream>>>(features, Hp, Hv, Wp1, bp1, Wv1, bv1, meta, out);
  }
}